// Round 1
// baseline (76.776 us; speedup 1.0000x reference)
//
#include <hip/hip_runtime.h>

// AdaIN: per-(b,c) channel over H*W=4096 spatial elements (fp32 in/out).
// out = (soft - mean(soft)) / max(std(soft),eps) * max(std(z),eps) + mean(z)
// std is unbiased (ddof=1). One block per channel; soft kept in registers so
// each input byte is read from HBM exactly once. Memory-bound: ~402 MB total.

constexpr int SPATIAL    = 4096;                 // H*W
constexpr int NTHREADS   = 256;                  // 4 waves
constexpr int VEC_PER_T  = SPATIAL / 4 / NTHREADS; // 4 float4 per thread
constexpr float EPS      = 1e-5f;

__global__ __launch_bounds__(NTHREADS) void adain_kernel(
    const float* __restrict__ soft,
    const float* __restrict__ z,
    float* __restrict__ out)
{
    const int ch = blockIdx.x;                    // flattened b*C + c
    const size_t base = (size_t)ch * SPATIAL;
    const int tid = threadIdx.x;

    const float4* s4 = reinterpret_cast<const float4*>(soft + base);
    const float4* z4 = reinterpret_cast<const float4*>(z + base);

    // Load soft into registers (stays resident), accumulate both stats.
    float4 sv[VEC_PER_T];
    float s_sum = 0.f, s_ss = 0.f, z_sum = 0.f, z_ss = 0.f;
#pragma unroll
    for (int k = 0; k < VEC_PER_T; ++k) {
        float4 v = s4[k * NTHREADS + tid];
        sv[k] = v;
        s_sum += (v.x + v.y) + (v.z + v.w);
        s_ss  += (v.x * v.x + v.y * v.y) + (v.z * v.z + v.w * v.w);
        float4 u = z4[k * NTHREADS + tid];
        z_sum += (u.x + u.y) + (u.z + u.w);
        z_ss  += (u.x * u.x + u.y * u.y) + (u.z * u.z + u.w * u.w);
    }

    // 64-lane wave butterfly reduce (4 values).
#pragma unroll
    for (int off = 32; off > 0; off >>= 1) {
        s_sum += __shfl_down(s_sum, off);
        s_ss  += __shfl_down(s_ss,  off);
        z_sum += __shfl_down(z_sum, off);
        z_ss  += __shfl_down(z_ss,  off);
    }

    // Cross-wave reduce through tiny LDS patch (4 waves x 4 values).
    __shared__ float red[4][4];
    const int wave = tid >> 6;
    const int lane = tid & 63;
    if (lane == 0) {
        red[wave][0] = s_sum;
        red[wave][1] = s_ss;
        red[wave][2] = z_sum;
        red[wave][3] = z_ss;
    }
    __syncthreads();
    const float ts_sum = (red[0][0] + red[1][0]) + (red[2][0] + red[3][0]);
    const float ts_ss  = (red[0][1] + red[1][1]) + (red[2][1] + red[3][1]);
    const float tz_sum = (red[0][2] + red[1][2]) + (red[2][2] + red[3][2]);
    const float tz_ss  = (red[0][3] + red[1][3]) + (red[2][3] + red[3][3]);

    const float inv_n   = 1.0f / (float)SPATIAL;
    const float inv_nm1 = 1.0f / (float)(SPATIAL - 1);

    const float s_mean = ts_sum * inv_n;
    const float s_var  = (ts_ss - ts_sum * s_mean) * inv_nm1;
    const float s_std  = fmaxf(sqrtf(fmaxf(s_var, 0.f)), EPS);
    const float z_mean = tz_sum * inv_n;
    const float z_var  = (tz_ss - tz_sum * z_mean) * inv_nm1;
    const float z_std  = fmaxf(sqrtf(fmaxf(z_var, 0.f)), EPS);

    const float scale = z_std / s_std;
    const float shift = z_mean - s_mean * scale;

    float4* o4 = reinterpret_cast<float4*>(out + base);
#pragma unroll
    for (int k = 0; k < VEC_PER_T; ++k) {
        float4 v = sv[k];
        float4 r;
        r.x = fmaf(v.x, scale, shift);
        r.y = fmaf(v.y, scale, shift);
        r.z = fmaf(v.z, scale, shift);
        r.w = fmaf(v.w, scale, shift);
        o4[k * NTHREADS + tid] = r;
    }
}

extern "C" void kernel_launch(void* const* d_in, const int* in_sizes, int n_in,
                              void* d_out, int out_size, void* d_ws, size_t ws_size,
                              hipStream_t stream) {
    const float* soft = (const float*)d_in[0];
    const float* z    = (const float*)d_in[1];
    float* out        = (float*)d_out;

    const int channels = in_sizes[0] / SPATIAL;   // B*C = 8192
    adain_kernel<<<channels, NTHREADS, 0, stream>>>(soft, z, out);
}

// Round 3
// 62.154 us; speedup vs baseline: 1.2353x; 1.2353x over previous
//
#include <hip/hip_runtime.h>

// AdaIN: per-(b,c) channel over H*W=4096 spatial elements (fp32 in/out).
// out = (soft - mean(soft)) / max(std(soft),eps) * max(std(z),eps) + mean(z)
// std is unbiased (ddof=1). One block per channel; soft kept in registers so
// each input byte is read from HBM exactly once.
//
// R3: non-temporal stores via native clang vector type (R2 failed to compile:
// __builtin_nontemporal_store rejects HIP_vector_type). Output is write-once;
// streaming it past the 256 MB LLC should keep the 268 MB of inputs resident
// (R1 measured 50% read hit-rate / FETCH=134 MB from write-allocate evictions).

constexpr int SPATIAL    = 4096;                 // H*W
constexpr int NTHREADS   = 256;                  // 4 waves
constexpr int VEC_PER_T  = SPATIAL / 4 / NTHREADS; // 4 float4 per thread
constexpr float EPS      = 1e-5f;

// Native clang vector type: accepted by __builtin_nontemporal_store,
// layout-identical to float4 (16 B, 4-float).
typedef float f32x4 __attribute__((ext_vector_type(4)));

__global__ __launch_bounds__(NTHREADS) void adain_kernel(
    const float* __restrict__ soft,
    const float* __restrict__ z,
    float* __restrict__ out)
{
    const int ch = blockIdx.x;                    // flattened b*C + c
    const size_t base = (size_t)ch * SPATIAL;
    const int tid = threadIdx.x;

    const float4* s4 = reinterpret_cast<const float4*>(soft + base);
    const float4* z4 = reinterpret_cast<const float4*>(z + base);

    // Load soft into registers (stays resident), accumulate both stats.
    float4 sv[VEC_PER_T];
    float s_sum = 0.f, s_ss = 0.f, z_sum = 0.f, z_ss = 0.f;
#pragma unroll
    for (int k = 0; k < VEC_PER_T; ++k) {
        float4 v = s4[k * NTHREADS + tid];
        sv[k] = v;
        s_sum += (v.x + v.y) + (v.z + v.w);
        s_ss  += (v.x * v.x + v.y * v.y) + (v.z * v.z + v.w * v.w);
        float4 u = z4[k * NTHREADS + tid];
        z_sum += (u.x + u.y) + (u.z + u.w);
        z_ss  += (u.x * u.x + u.y * u.y) + (u.z * u.z + u.w * u.w);
    }

    // 64-lane wave butterfly reduce (4 values).
#pragma unroll
    for (int off = 32; off > 0; off >>= 1) {
        s_sum += __shfl_down(s_sum, off);
        s_ss  += __shfl_down(s_ss,  off);
        z_sum += __shfl_down(z_sum, off);
        z_ss  += __shfl_down(z_ss,  off);
    }

    // Cross-wave reduce through tiny LDS patch (4 waves x 4 values).
    __shared__ float red[4][4];
    const int wave = tid >> 6;
    const int lane = tid & 63;
    if (lane == 0) {
        red[wave][0] = s_sum;
        red[wave][1] = s_ss;
        red[wave][2] = z_sum;
        red[wave][3] = z_ss;
    }
    __syncthreads();
    const float ts_sum = (red[0][0] + red[1][0]) + (red[2][0] + red[3][0]);
    const float ts_ss  = (red[0][1] + red[1][1]) + (red[2][1] + red[3][1]);
    const float tz_sum = (red[0][2] + red[1][2]) + (red[2][2] + red[3][2]);
    const float tz_ss  = (red[0][3] + red[1][3]) + (red[2][3] + red[3][3]);

    const float inv_n   = 1.0f / (float)SPATIAL;
    const float inv_nm1 = 1.0f / (float)(SPATIAL - 1);

    const float s_mean = ts_sum * inv_n;
    const float s_var  = (ts_ss - ts_sum * s_mean) * inv_nm1;
    const float s_std  = fmaxf(sqrtf(fmaxf(s_var, 0.f)), EPS);
    const float z_mean = tz_sum * inv_n;
    const float z_var  = (tz_ss - tz_sum * z_mean) * inv_nm1;
    const float z_std  = fmaxf(sqrtf(fmaxf(z_var, 0.f)), EPS);

    const float scale = z_std / s_std;
    const float shift = z_mean - s_mean * scale;

    f32x4* o4 = reinterpret_cast<f32x4*>(out + base);
#pragma unroll
    for (int k = 0; k < VEC_PER_T; ++k) {
        float4 v = sv[k];
        f32x4 r;
        r.x = fmaf(v.x, scale, shift);
        r.y = fmaf(v.y, scale, shift);
        r.z = fmaf(v.z, scale, shift);
        r.w = fmaf(v.w, scale, shift);
        // Stream past LLC: output is write-once, keep LLC for the inputs.
        __builtin_nontemporal_store(r, &o4[k * NTHREADS + tid]);
    }
}

extern "C" void kernel_launch(void* const* d_in, const int* in_sizes, int n_in,
                              void* d_out, int out_size, void* d_ws, size_t ws_size,
                              hipStream_t stream) {
    const float* soft = (const float*)d_in[0];
    const float* z    = (const float*)d_in[1];
    float* out        = (float*)d_out;

    const int channels = in_sizes[0] / SPATIAL;   // B*C = 8192
    adain_kernel<<<channels, NTHREADS, 0, stream>>>(soft, z, out);
}